// Round 9
// baseline (236.999 us; speedup 1.0000x reference)
//
#include <hip/hip_runtime.h>

// ws layout (32-bit word offsets). LB arrays are bf16-packed (2 per word):
// LB[j][d] has MP rows, KS bf16 columns (row stride KS), row p holds
// [ L[p][0..M-1], A_mu[p][0], A_mu[p][1], zeros... ]
#define LB0_OFF 0         // 16 * (64*72/2)   = 16*2304  = 36864
#define LB1_OFF 36864     // 16 * (112*136/2) = 16*7616  = 121856
#define LB2_OFF 158720    // 16 * (160*168/2) = 16*13440 = 215040
#define PART_OFF 373760   // 48 partial ldj sums (float)
// 48 ready-flags, carved INSIDE the LB2 pad region (d=15, row p=159, word
// cols 0..47). p=159 >= M=150 -> its MFMA output column is discarded, so
// arbitrary bytes here are benign for apply. build(2,15) skips these words.
// LB2_OFF + 15*13440 + 159*84 = 373676; +48 = 373724 <= PART_OFF. Zeroed by
// a 192-B hipMemsetAsync before the fused dispatch each iteration.
#define FLAGS_OFF 373676

typedef __attribute__((ext_vector_type(8))) short bf8_t;    // 8 bf16 (4 VGPR)
typedef __attribute__((ext_vector_type(8))) unsigned short us8_t;
typedef __attribute__((ext_vector_type(4))) float f32x4;

__device__ __forceinline__ int tri_i(int p) { return (p * (p + 1)) >> 1; }

// Collision-free 16B-aligned packed-triangle layout: row p is padded to
// 4*ceil((p+1)/4) floats. Cumulative start (closed form, verified):
//   roff(p) = 4*(T+1)*(2T+r),  T = p>>2, r = p&3
// roff(159)+159 = 13119 -> sS size 13120 exactly covers all rows.
__device__ __forceinline__ int roff(int p) {
  const int T = p >> 2, r = p & 3;
  return ((T + 1) * (2 * T + r)) << 2;
}

__device__ __forceinline__ void tri_decode(int e, int& r, int& c) {
  r = (int)((sqrtf(8.0f * (float)e + 1.0f) - 1.0f) * 0.5f);
  if (tri_i(r + 1) <= e) ++r;
  if (tri_i(r) > e) --r;
  c = e - tri_i(r);
}

// fp32 -> bf16, round-nearest-even
__device__ __forceinline__ unsigned short f2bf(float f) {
  unsigned u = __builtin_bit_cast(unsigned, f);
  u = (u + 0x7FFFu + ((u >> 16) & 1u)) >> 16;
  return (unsigned short)u;
}
__device__ __forceinline__ float bf2f(unsigned short h) {
  return __builtin_bit_cast(float, ((unsigned)h) << 16);
}

// uniform-lane broadcast via v_readlane (no DS pipe, low latency)
__device__ __forceinline__ float blane(float v, int l) {
  return __builtin_bit_cast(float, __builtin_amdgcn_readlane(__builtin_bit_cast(int, v), l));
}
__device__ __forceinline__ float fastrcp(float x) { return __builtin_amdgcn_rcpf(x); }

#define BNT 512   // build threads (8 waves)
#define EPSF 1e-4f

// ---------------------------------------------------------------------------
// Build (FROZEN from R7, known-good 58.3us): per (j,d) Sigma (padded to MP,
// identity tail), blocked raw-Schur Cholesky (bw=16) with MFMA phase C.
// Only change: skip the 48 flag words in the LB write (J==2, d==15, p==159).
// ---------------------------------------------------------------------------
template <int J>
__device__ __forceinline__ void build_impl(int d,
                                           const float* __restrict__ ts,
                                           const float* __restrict__ log_tau,
                                           float* __restrict__ ws,
                                           float* sS,
                                           unsigned short* sUc, unsigned short* sWc,
                                           float* stj, float* sAmu, float* sKp,
                                           float* red)
{
  constexpr int M  = (J + 1) * 50;
  constexpr int MP = (J == 0) ? 64 : ((J == 1) ? 112 : 160);
  constexpr int KS = (J == 0) ? 72 : ((J == 1) ? 136 : 168);
  constexpr int LBOFF = (J == 0) ? LB0_OFF : ((J == 1) ? LB1_OFF : LB2_OFF);
  constexpr float TPSJ = (J == 0) ? 10.0f : ((J == 1) ? 20.0f : 30.0f);
  constexpr int KW = KS / 2;
  constexpr int TOT = (MP * (MP + 1)) / 2;
  constexpr int NPAN = MP / 16;

  const int tid  = threadIdx.x;
  const int lane = tid & 63;
  const int wid  = tid >> 6;        // 8 waves

  const float tau = expf(log_tau[d]);
  const float cc = 1.0f / (2.0f * tau * tau);

  for (int i = tid; i < M; i += BNT) stj[i] = ts[i];
  __syncthreads();

  const float k01 = expf(-TPSJ * TPSJ * cc);
  const float det = 1.0f - k01 * k01;
  const float i00 = 1.0f / det;
  const float i01 = -k01 / det;

  for (int p = tid; p < M; p += BNT) {
    float tp = stj[p];
    float kp0 = expf(-tp * tp * cc);
    float dt = tp - TPSJ;
    float kp1 = expf(-dt * dt * cc);
    sKp[p * 2 + 0] = kp0; sKp[p * 2 + 1] = kp1;
    sAmu[p * 2 + 0] = fmaf(kp0, i00, kp1 * i01);
    sAmu[p * 2 + 1] = fmaf(kp0, i01, kp1 * i00);
  }
  __syncthreads();

  // Sigma, padded: rows >= M are identity -> log contrib 0, L tail ignored.
  for (int e = tid; e < TOT; e += BNT) {
    int r, q;
    tri_decode(e, r, q);
    float v;
    if (r < M) {
      float dq = stj[r] - stj[q];
      v = expf(-dq * dq * cc)
        - fmaf(sAmu[r * 2], sKp[q * 2], sAmu[r * 2 + 1] * sKp[q * 2 + 1]);
      if (r == q) v += EPSF;
    } else {
      v = (r == q) ? 1.0f : 0.0f;
    }
    sS[roff(r) + q] = v;
  }
  __syncthreads();

  // ---- Blocked raw-Schur Cholesky, bw == 16 always ----
  const int tr = lane & 15;
#pragma unroll 1
  for (int pb = 0; pb < NPAN; ++pb) {
    const int kb = pb << 4;
    const int be = kb + 16;
    const int rbase = roff(kb + tr) + kb;   // 16B-aligned

    // phase A: diag block factor in registers, replicated in waves 0..2.
    float rd[16];
    float invd[16];
    if (wid < 3) {
      const float4* rp = (const float4*)&sS[rbase];
#pragma unroll
      for (int c4 = 0; c4 < 4; ++c4) *(float4*)&rd[c4 * 4] = rp[c4];
#pragma unroll
      for (int kk = 0; kk < 15; ++kk) {
        const float dkk = fmaxf(blane(rd[kk], kk), EPSF);   // clamp (no-op in exact math)
        const float ri = fastrcp(dkk);
        invd[kk] = ri;
        const float c = -rd[kk] * ri;
#pragma unroll
        for (int q2 = kk + 1; q2 < 16; ++q2) {
          const float cq2 = blane(rd[kk], q2);
          if (tr > kk && q2 <= tr) rd[q2] = fmaf(c, cq2, rd[q2]);
        }
      }
      invd[15] = fastrcp(fmaxf(blane(rd[15], 15), EPSF));
    }

    // phase B (no barrier after A: same waves): row-solve, 1 thread per row.
    // Emits split-bf16 rows for the MFMA trailing update.
    if (be < MP) {
      const int i = be + tid;
      if (i < MP) {
        const int base = roff(i) + kb;      // 16B-aligned
        float r[16];
        const float4* rp = (const float4*)&sS[base];
#pragma unroll
        for (int c4 = 0; c4 < 4; ++c4) *(float4*)&r[c4 * 4] = rp[c4];
#pragma unroll
        for (int kk = 0; kk < 15; ++kk) {
          const float c = r[kk] * invd[kk];
#pragma unroll
          for (int q = kk + 1; q < 16; ++q)
            r[q] = fmaf(-c, blane(rd[kk], q), r[q]);
        }
        float4* sp = (float4*)&sS[base];
#pragma unroll
        for (int c4 = 0; c4 < 4; ++c4) sp[c4] = *(float4*)&r[c4 * 4];
        // split-bf16: Uc = [hi(u) | lo(u)], Wc = [hi(-w) | lo(-w)], K=32
        unsigned short uc[32], wc[32];
#pragma unroll
        for (int t = 0; t < 16; ++t) {
          const float uv = r[t];
          const unsigned short uhh = f2bf(uv);
          uc[t] = uhh; uc[16 + t] = f2bf(uv - bf2f(uhh));
          const float wv = -(r[t] * invd[t]);
          const unsigned short whh = f2bf(wv);
          wc[t] = whh; wc[16 + t] = f2bf(wv - bf2f(whh));
        }
        unsigned short* ucp = &sUc[i * 32];
        unsigned short* wcp = &sWc[i * 32];
#pragma unroll
        for (int c8 = 0; c8 < 4; ++c8) {
          *(us8_t*)&ucp[c8 * 8] = *(us8_t*)&uc[c8 * 8];
          *(us8_t*)&wcp[c8 * 8] = *(us8_t*)&wc[c8 * 8];
        }
      }
    }
    __syncthreads();

    // factored diag -> sS (predicated: q > tr is beyond row's valid cols)
    if (wid == 0 && lane < 16) {
#pragma unroll
      for (int q = 0; q < 16; ++q) if (q <= tr) sS[rbase + q] = rd[q];
    }

    // phase C (MFMA): trailing Schur update, one 16x16 tile per iteration.
    // D = S_tile + [Wh|Wl].[Uh|Ul]^T + [Wl|Wh].[Uh|Ul]^T  (W pre-negated).
    if (be < MP) {
      const int ntr = (MP - be) >> 4;
      const int ntiles = (ntr * (ntr + 1)) >> 1;
      const int rloc = lane & 15;
      const int koff = (lane >> 4) * 8;
      for (int t = wid; t < ntiles; t += 8) {
        int ta, tb;
        tri_decode(t, ta, tb);              // tb <= ta
        const int R0 = be + (ta << 4);
        const int Q0 = be + (tb << 4);
        const bf8_t af  = *(const bf8_t*)&sWc[(R0 + rloc) * 32 + koff];
        const bf8_t af2 = *(const bf8_t*)&sWc[(R0 + rloc) * 32 + (koff ^ 16)];
        const bf8_t bfv = *(const bf8_t*)&sUc[(Q0 + rloc) * 32 + koff];
        const int drow = R0 + (lane >> 4) * 4;
        const int qq = Q0 + rloc;
        int ra[4];
        f32x4 acc;
#pragma unroll
        for (int e = 0; e < 4; ++e) {
          ra[e] = roff(drow + e) + qq;      // qq>row reads in-bounds junk,
          acc[e] = sS[ra[e]];               // write-predicated below
        }
        acc = __builtin_amdgcn_mfma_f32_16x16x32_bf16(af,  bfv, acc, 0, 0, 0);
        acc = __builtin_amdgcn_mfma_f32_16x16x32_bf16(af2, bfv, acc, 0, 0, 0);
#pragma unroll
        for (int e = 0; e < 4; ++e)
          if (qq <= drow + e) sS[ra[e]] = acc[e];
      }
    }
    __syncthreads();
  }

  // ldj partial: sum 0.5*log(d_p) over real rows; wave reduce
  float part = 0.0f;
  for (int p = tid; p < M; p += BNT)
    part += 0.5f * logf(fmaxf(sS[roff(p) + p], EPSF));
#pragma unroll
  for (int off = 32; off > 0; off >>= 1) part += __shfl_down(part, off);
  if (lane == 0) red[wid] = part;
  __syncthreads();
  if (tid == 0) {
    float s = 0.0f;
#pragma unroll
    for (int w8 = 0; w8 < 8; ++w8) s += red[w8];
    ws[PART_OFF + J * 16 + d] = s;
  }

  // LB (bf16) write: row p, cols k: [L[p][0..M-1], A0[p], A1[p], 0 pad]
  unsigned* LBg = (unsigned*)ws + LBOFF + d * (MP * KW);
  constexpr int NWORDS = MP * KW;
  for (int idx = tid; idx < NWORDS; idx += BNT) {
    const int p = idx / KW;
    if constexpr (J == 2) {
      // flag words live in the discarded pad row p=159 of d==15 — never
      // overwrite them (the cross-block ready flags).
      if (d == 15 && p == 159 && (idx - p * KW) < 48) continue;
    }
    const int k0 = (idx - p * KW) * 2;
    unsigned short h[2];
#pragma unroll
    for (int e = 0; e < 2; ++e) {
      const int k = k0 + e;
      float v = 0.0f;
      if (p < M) {
        if (k < M) {
          if (k <= p) {
            const float dq = fmaxf(sS[roff(k) + k], EPSF);
            v = (k == p) ? sqrtf(dq) : sS[roff(p) + k] * rsqrtf(dq);
          }
        } else if (k == M)     v = sAmu[p * 2 + 0];
        else if (k == M + 1)   v = sAmu[p * 2 + 1];
      }
      h[e] = f2bf(v);
    }
    LBg[idx] = (unsigned)h[0] | ((unsigned)h[1] << 16);
  }
}

// ---------------------------------------------------------------------------
// Apply tile (FROZEN R5 math): out[b,p] = sum_k Z'[b,k] * LB[p,k], 64 b-rows.
// Parameterized on tid (0..255 within the executing 4-wave group) and an
// optional ready-flag: staging + passthrough run flag-free; the LB-consuming
// MFMA loop waits for the flag (acquire). Bounded spin -> no hang possible.
// ---------------------------------------------------------------------------
template <int M, int MP, int KS, int KT, int TOFF, int OOFF, int LBOFF>
__device__ __forceinline__ void apply_impl(const float* __restrict__ z,
                                           const unsigned* __restrict__ wsu,
                                           float* __restrict__ out,
                                           char* smem, int blk, int tid,
                                           const unsigned* flg)
{
  constexpr int PT = MP / 16;           // p-tiles
  constexpr int CK = KS / 8;            // 8-col chunks per Z row
  const int d   = blk & 15;
  const int bs0 = (blk >> 4) * 64;      // 64-row group
  const int lane = tid & 63;
  const int wv   = tid >> 6;            // 4 waves, each owns a p-tile range

  unsigned short* Zs = (unsigned short*)smem;   // 64 x KS bf16

  // stage Z' tile (bf16): row r, cols k -> z[row][TOFF+k] | zf | zl | 0
  for (int idx = tid; idx < 64 * CK; idx += 256) {
    const int r = idx / CK;             // constexpr CK -> magic mul
    const int k0 = (idx - r * CK) * 8;
    const float* zr = z + (size_t)((bs0 + r) * 16 + d) * 302;
    us8_t v;
    if (k0 + 8 <= M) {
#pragma unroll
      for (int t = 0; t < 4; ++t) {
        const float2 f = *(const float2*)(zr + TOFF + k0 + 2 * t);
        v[2 * t]     = f2bf(f.x);
        v[2 * t + 1] = f2bf(f.y);
      }
    } else {
#pragma unroll
      for (int e = 0; e < 8; ++e) {
        const int k = k0 + e;
        float f;
        if (k < M)           f = zr[TOFF + k];
        else if (k == M)     f = zr[0];
        else if (k == M + 1) f = zr[1];
        else                 f = 0.0f;
        v[e] = f2bf(f);
      }
    }
    *(us8_t*)&Zs[r * KS + k0] = v;
  }

  // zf / zl pass-through columns (exact fp32), 64 rows x 2
  if (tid < 128) {
    const int r = tid >> 1;
    const int which = tid & 1;
    const float* zr = z + (size_t)((bs0 + r) * 16 + d) * 302;
    out[(size_t)((bs0 + r) * 16 + d) * 306 + OOFF + (which ? (M + 1) : 0)] = zr[which];
  }
  __syncthreads();

  // A fragments for all 4 row-tiles: rt*16 + (lane&15), koff = (lane>>4)*8
  bf8_t afr[4][KT];
  {
    const int arow = lane & 15;
    const int koff = (lane >> 4) * 8;
#pragma unroll
    for (int rt = 0; rt < 4; ++rt)
#pragma unroll
      for (int kt = 0; kt < KT; ++kt)
        afr[rt][kt] = *(const bf8_t*)&Zs[(rt * 16 + arow) * KS + kt * 32 + koff];
  }

  // wait for this (j,d)'s LB to be published (fused dispatch only)
  if (flg) {
    for (int it = 0; it < (1 << 20); ++it) {
      if (__hip_atomic_load(flg, __ATOMIC_ACQUIRE, __HIP_MEMORY_SCOPE_AGENT)) break;
      __builtin_amdgcn_s_sleep(2);
    }
  }

  const unsigned short* LBd = (const unsigned short*)(wsu + LBOFF + d * (MP * (KS / 2)));
  const int pt0 = (PT * wv) >> 2;       // disjoint p-tile range per wave
  const int pt1 = (PT * (wv + 1)) >> 2;
  for (int pt = pt0; pt < pt1; ++pt) {
    const int p = pt * 16 + (lane & 15);
    const unsigned short* bb = &LBd[p * KS + (lane >> 4) * 8];
    bf8_t bfr[KT];
#pragma unroll
    for (int kt = 0; kt < KT; ++kt)
      bfr[kt] = *(const bf8_t*)&bb[kt * 32];   // 16B global load (L2)
#pragma unroll
    for (int rt = 0; rt < 4; ++rt) {
      f32x4 acc = {0.0f, 0.0f, 0.0f, 0.0f};
#pragma unroll
      for (int kt = 0; kt < KT; ++kt)
        acc = __builtin_amdgcn_mfma_f32_16x16x32_bf16(afr[rt][kt], bfr[kt], acc, 0, 0, 0);
      if (p < M) {
        const int rbase = bs0 + rt * 16 + (lane >> 4) * 4;
#pragma unroll
        for (int e = 0; e < 4; ++e)
          out[(size_t)((rbase + e) * 16 + d) * 306 + OOFF + 1 + p] = acc[e];
      }
    }
  }
}

// big-chunk g in [0,512): two 64-row sub-chunks run by waves 0-3 / 4-7.
// g < 256 -> j0 sub-chunks 2g,2g+1 ; g >= 256 -> j1 sub-chunks.
__device__ __forceinline__ void run_bigchunk(int g, const float* z,
                                             const unsigned* wsu, float* out,
                                             char* smem, unsigned* flags)
{
  const int tid  = threadIdx.x;
  const int half = tid >> 8;
  const int ltid = tid & 255;
  char* sm = smem + half * 21504;
  if (g < 256) {
    const int sub = g * 2 + half;
    apply_impl<50, 64, 72, 2, 2, 0, LB0_OFF>(z, wsu, out, sm, sub, ltid,
                                             &flags[sub & 15]);
  } else {
    const int sub = (g - 256) * 2 + half;
    apply_impl<100, 112, 136, 4, 52, 52, LB1_OFF>(z, wsu, out, sm, sub, ltid,
                                                  &flags[16 + (sub & 15)]);
  }
}

// ---------------------------------------------------------------------------
// D1 (fused): blocks 0-47 = build (then publish flag); blocks 48-511 = j0/j1
// apply workers (stage flag-free, spin for LB, MFMA). Grid 512 x 512thr,
// LDS 76032 (2 blocks/CU), VGPR capped 128 by launch bounds -> entire grid
// co-resident -> spin-wait safe; bounded spin caps any pathology at ~100ms.
// Chunk schedule: worker w=bid-48: g=w (j0 ready ~15us / j1 ~30us);
// workers w<48 take a second chunk g=464+w (j1). j2-build blocks take none
// (keeps the 58us critical path clean).
// ---------------------------------------------------------------------------
__global__ __launch_bounds__(512, 4) void fused_kernel(const float* __restrict__ z,
                                                       const float* __restrict__ ts,
                                                       const float* __restrict__ log_tau,
                                                       float* __restrict__ ws,
                                                       float* __restrict__ out)
{
  __shared__ __attribute__((aligned(16))) char smem[76032];
  unsigned* flags = (unsigned*)ws + FLAGS_OFF;
  const int bid = blockIdx.x;
  if (bid < 48) {
    float* sS           = (float*)smem;                        // 52480 B
    unsigned short* sUc = (unsigned short*)(smem + 52480);     // 10240 B
    unsigned short* sWc = (unsigned short*)(smem + 62720);     // 10240 B
    float* stj          = (float*)(smem + 72960);              //   608 B
    float* sAmu         = (float*)(smem + 73568);              //  1216 B
    float* sKp          = (float*)(smem + 74784);              //  1216 B
    float* red          = (float*)(smem + 76000);              //    32 B
    const int j = bid >> 4;
    const int d = bid & 15;
    if (j == 0)      build_impl<0>(d, ts, log_tau, ws, sS, sUc, sWc, stj, sAmu, sKp, red);
    else if (j == 1) build_impl<1>(d, ts, log_tau, ws, sS, sUc, sWc, stj, sAmu, sKp, red);
    else             build_impl<2>(d, ts, log_tau, ws, sS, sUc, sWc, stj, sAmu, sKp, red);
    __syncthreads();                 // all LB writes done
    __threadfence();                 // agent-scope release of LB + partial
    if (threadIdx.x == 0)
      __hip_atomic_store(&flags[bid], 1u, __ATOMIC_RELEASE, __HIP_MEMORY_SCOPE_AGENT);
  } else {
    const int w = bid - 48;
    run_bigchunk(w, z, (const unsigned*)ws, out, smem, flags);
    if (w < 48) {
      __syncthreads();               // Zs reuse safety between chunks
      run_bigchunk(464 + w, z, (const unsigned*)ws, out, smem, flags);
    }
  }
}

// ---------------------------------------------------------------------------
// D2: j2 apply (runs after fused dispatch completes -> no flags needed)
// + fused finalize in block 0.
// ---------------------------------------------------------------------------
__global__ __launch_bounds__(256) void apply_j2_kernel(const float* __restrict__ z,
                                                       const unsigned* __restrict__ wsu,
                                                       float* __restrict__ out,
                                                       const float* __restrict__ part,
                                                       const float* __restrict__ sldj,
                                                       int last)
{
  __shared__ __attribute__((aligned(16))) char smem[21504];
  if (blockIdx.x == 0 && threadIdx.x == 0) {
    float s = sldj[0];
#pragma unroll
    for (int i = 0; i < 48; ++i) s += part[i];
    out[last] = s;
  }
  apply_impl<150, 160, 168, 5, 152, 154, LB2_OFF>(z, wsu, out, smem,
                                                  (int)blockIdx.x, (int)threadIdx.x,
                                                  nullptr);
}

extern "C" void kernel_launch(void* const* d_in, const int* in_sizes, int n_in,
                              void* d_out, int out_size, void* d_ws, size_t ws_size,
                              hipStream_t stream)
{
  const float* z       = (const float*)d_in[0];  // (16,128,16,302)
  const float* ts      = (const float*)d_in[1];  // (3,50) flat
  const float* log_tau = (const float*)d_in[2];  // (16,)
  const float* sldj    = (const float*)d_in[3];  // scalar
  float* out = (float*)d_out;                    // 16*128*16*306 + 1
  float* ws  = (float*)d_ws;

  // zero the 48 ready-flags (graph-capturable, ~1us)
  hipMemsetAsync((char*)d_ws + (size_t)FLAGS_OFF * 4, 0, 48 * 4, stream);
  hipLaunchKernelGGL(fused_kernel, dim3(512), dim3(512), 0, stream,
                     z, ts, log_tau, ws, out);
  hipLaunchKernelGGL(apply_j2_kernel, dim3(512), dim3(256), 0, stream,
                     z, (const unsigned*)ws, out,
                     ws + PART_OFF, sldj, out_size - 1);
}

// Round 10
// 197.903 us; speedup vs baseline: 1.1976x; 1.1976x over previous
//
#include <hip/hip_runtime.h>

// ws layout (32-bit word offsets). LB arrays are bf16-packed (2 per word):
// LB[j][d] has MP rows, KS bf16 columns (row stride KS), row p holds
// [ L[p][0..M-1], A_mu[p][0], A_mu[p][1], zeros... ]
#define LB0_OFF 0         // 16 * (64*72/2)   = 16*2304  = 36864
#define LB1_OFF 36864     // 16 * (112*136/2) = 16*7616  = 121856
#define LB2_OFF 158720    // 16 * (160*168/2) = 16*13440 = 215040
#define PART_OFF 373760   // 48 partial ldj sums (float)

typedef __attribute__((ext_vector_type(8))) short bf8_t;    // 8 bf16 (4 VGPR)
typedef __attribute__((ext_vector_type(8))) unsigned short us8_t;
typedef __attribute__((ext_vector_type(4))) float f32x4;
typedef __attribute__((ext_vector_type(2))) float f32x2;

__device__ __forceinline__ int tri_i(int p) { return (p * (p + 1)) >> 1; }

// Collision-free 16B-aligned packed-triangle layout: row p is padded to
// 4*ceil((p+1)/4) floats. Cumulative start (closed form, verified):
//   roff(p) = 4*(T+1)*(2T+r),  T = p>>2, r = p&3
// roff(159)+159 = 13119 -> sS size 13120 exactly covers all rows.
__device__ __forceinline__ int roff(int p) {
  const int T = p >> 2, r = p & 3;
  return ((T + 1) * (2 * T + r)) << 2;
}

__device__ __forceinline__ void tri_decode(int e, int& r, int& c) {
  r = (int)((sqrtf(8.0f * (float)e + 1.0f) - 1.0f) * 0.5f);
  if (tri_i(r + 1) <= e) ++r;
  if (tri_i(r) > e) --r;
  c = e - tri_i(r);
}

// fp32 -> bf16, round-nearest-even
__device__ __forceinline__ unsigned short f2bf(float f) {
  unsigned u = __builtin_bit_cast(unsigned, f);
  u = (u + 0x7FFFu + ((u >> 16) & 1u)) >> 16;
  return (unsigned short)u;
}
__device__ __forceinline__ float bf2f(unsigned short h) {
  return __builtin_bit_cast(float, ((unsigned)h) << 16);
}

// uniform-lane broadcast via v_readlane (no DS pipe, low latency)
__device__ __forceinline__ float blane(float v, int l) {
  return __builtin_bit_cast(float, __builtin_amdgcn_readlane(__builtin_bit_cast(int, v), l));
}
__device__ __forceinline__ float fastrcp(float x) { return __builtin_amdgcn_rcpf(x); }

#define BNT 512   // build_kernel threads (8 waves)
#define EPSF 1e-4f

// ---------------------------------------------------------------------------
// Kernel A (FROZEN from R7, known-good 58.3us): per (j,d) Sigma (padded to
// MP, identity tail), blocked raw-Schur Cholesky (bw=16) with MFMA phase C.
// ---------------------------------------------------------------------------
template <int J>
__device__ __forceinline__ void build_impl(int d,
                                           const float* __restrict__ ts,
                                           const float* __restrict__ log_tau,
                                           float* __restrict__ ws,
                                           float* sS,
                                           unsigned short* sUc, unsigned short* sWc,
                                           float* stj, float* sAmu, float* sKp,
                                           float* red)
{
  constexpr int M  = (J + 1) * 50;
  constexpr int MP = (J == 0) ? 64 : ((J == 1) ? 112 : 160);
  constexpr int KS = (J == 0) ? 72 : ((J == 1) ? 136 : 168);
  constexpr int LBOFF = (J == 0) ? LB0_OFF : ((J == 1) ? LB1_OFF : LB2_OFF);
  constexpr float TPSJ = (J == 0) ? 10.0f : ((J == 1) ? 20.0f : 30.0f);
  constexpr int KW = KS / 2;
  constexpr int TOT = (MP * (MP + 1)) / 2;
  constexpr int NPAN = MP / 16;

  const int tid  = threadIdx.x;
  const int lane = tid & 63;
  const int wid  = tid >> 6;        // 8 waves

  const float tau = expf(log_tau[d]);
  const float cc = 1.0f / (2.0f * tau * tau);

  for (int i = tid; i < M; i += BNT) stj[i] = ts[i];
  __syncthreads();

  const float k01 = expf(-TPSJ * TPSJ * cc);
  const float det = 1.0f - k01 * k01;
  const float i00 = 1.0f / det;
  const float i01 = -k01 / det;

  for (int p = tid; p < M; p += BNT) {
    float tp = stj[p];
    float kp0 = expf(-tp * tp * cc);
    float dt = tp - TPSJ;
    float kp1 = expf(-dt * dt * cc);
    sKp[p * 2 + 0] = kp0; sKp[p * 2 + 1] = kp1;
    sAmu[p * 2 + 0] = fmaf(kp0, i00, kp1 * i01);
    sAmu[p * 2 + 1] = fmaf(kp0, i01, kp1 * i00);
  }
  __syncthreads();

  // Sigma, padded: rows >= M are identity -> log contrib 0, L tail ignored.
  for (int e = tid; e < TOT; e += BNT) {
    int r, q;
    tri_decode(e, r, q);
    float v;
    if (r < M) {
      float dq = stj[r] - stj[q];
      v = expf(-dq * dq * cc)
        - fmaf(sAmu[r * 2], sKp[q * 2], sAmu[r * 2 + 1] * sKp[q * 2 + 1]);
      if (r == q) v += EPSF;
    } else {
      v = (r == q) ? 1.0f : 0.0f;
    }
    sS[roff(r) + q] = v;
  }
  __syncthreads();

  // ---- Blocked raw-Schur Cholesky, bw == 16 always ----
  const int tr = lane & 15;
#pragma unroll 1
  for (int pb = 0; pb < NPAN; ++pb) {
    const int kb = pb << 4;
    const int be = kb + 16;
    const int rbase = roff(kb + tr) + kb;   // 16B-aligned

    // phase A: diag block factor in registers, replicated in waves 0..2.
    float rd[16];
    float invd[16];
    if (wid < 3) {
      const float4* rp = (const float4*)&sS[rbase];
#pragma unroll
      for (int c4 = 0; c4 < 4; ++c4) *(float4*)&rd[c4 * 4] = rp[c4];
#pragma unroll
      for (int kk = 0; kk < 15; ++kk) {
        const float dkk = fmaxf(blane(rd[kk], kk), EPSF);   // clamp (no-op in exact math)
        const float ri = fastrcp(dkk);
        invd[kk] = ri;
        const float c = -rd[kk] * ri;
#pragma unroll
        for (int q2 = kk + 1; q2 < 16; ++q2) {
          const float cq2 = blane(rd[kk], q2);
          if (tr > kk && q2 <= tr) rd[q2] = fmaf(c, cq2, rd[q2]);
        }
      }
      invd[15] = fastrcp(fmaxf(blane(rd[15], 15), EPSF));
    }

    // phase B (no barrier after A: same waves): row-solve, 1 thread per row.
    // Emits split-bf16 rows for the MFMA trailing update.
    if (be < MP) {
      const int i = be + tid;
      if (i < MP) {
        const int base = roff(i) + kb;      // 16B-aligned
        float r[16];
        const float4* rp = (const float4*)&sS[base];
#pragma unroll
        for (int c4 = 0; c4 < 4; ++c4) *(float4*)&r[c4 * 4] = rp[c4];
#pragma unroll
        for (int kk = 0; kk < 15; ++kk) {
          const float c = r[kk] * invd[kk];
#pragma unroll
          for (int q = kk + 1; q < 16; ++q)
            r[q] = fmaf(-c, blane(rd[kk], q), r[q]);
        }
        float4* sp = (float4*)&sS[base];
#pragma unroll
        for (int c4 = 0; c4 < 4; ++c4) sp[c4] = *(float4*)&r[c4 * 4];
        // split-bf16: Uc = [hi(u) | lo(u)], Wc = [hi(-w) | lo(-w)], K=32
        unsigned short uc[32], wc[32];
#pragma unroll
        for (int t = 0; t < 16; ++t) {
          const float uv = r[t];
          const unsigned short uhh = f2bf(uv);
          uc[t] = uhh; uc[16 + t] = f2bf(uv - bf2f(uhh));
          const float wv = -(r[t] * invd[t]);
          const unsigned short whh = f2bf(wv);
          wc[t] = whh; wc[16 + t] = f2bf(wv - bf2f(whh));
        }
        unsigned short* ucp = &sUc[i * 32];
        unsigned short* wcp = &sWc[i * 32];
#pragma unroll
        for (int c8 = 0; c8 < 4; ++c8) {
          *(us8_t*)&ucp[c8 * 8] = *(us8_t*)&uc[c8 * 8];
          *(us8_t*)&wcp[c8 * 8] = *(us8_t*)&wc[c8 * 8];
        }
      }
    }
    __syncthreads();

    // factored diag -> sS (predicated: q > tr is beyond row's valid cols)
    if (wid == 0 && lane < 16) {
#pragma unroll
      for (int q = 0; q < 16; ++q) if (q <= tr) sS[rbase + q] = rd[q];
    }

    // phase C (MFMA): trailing Schur update, one 16x16 tile per iteration.
    // D = S_tile + [Wh|Wl].[Uh|Ul]^T + [Wl|Wh].[Uh|Ul]^T  (W pre-negated).
    if (be < MP) {
      const int ntr = (MP - be) >> 4;
      const int ntiles = (ntr * (ntr + 1)) >> 1;
      const int rloc = lane & 15;
      const int koff = (lane >> 4) * 8;
      for (int t = wid; t < ntiles; t += 8) {
        int ta, tb;
        tri_decode(t, ta, tb);              // tb <= ta
        const int R0 = be + (ta << 4);
        const int Q0 = be + (tb << 4);
        const bf8_t af  = *(const bf8_t*)&sWc[(R0 + rloc) * 32 + koff];
        const bf8_t af2 = *(const bf8_t*)&sWc[(R0 + rloc) * 32 + (koff ^ 16)];
        const bf8_t bfv = *(const bf8_t*)&sUc[(Q0 + rloc) * 32 + koff];
        const int drow = R0 + (lane >> 4) * 4;
        const int qq = Q0 + rloc;
        int ra[4];
        f32x4 acc;
#pragma unroll
        for (int e = 0; e < 4; ++e) {
          ra[e] = roff(drow + e) + qq;      // qq>row reads in-bounds junk,
          acc[e] = sS[ra[e]];               // write-predicated below
        }
        acc = __builtin_amdgcn_mfma_f32_16x16x32_bf16(af,  bfv, acc, 0, 0, 0);
        acc = __builtin_amdgcn_mfma_f32_16x16x32_bf16(af2, bfv, acc, 0, 0, 0);
#pragma unroll
        for (int e = 0; e < 4; ++e)
          if (qq <= drow + e) sS[ra[e]] = acc[e];
      }
    }
    __syncthreads();
  }

  // ldj partial: sum 0.5*log(d_p) over real rows; wave reduce
  float part = 0.0f;
  for (int p = tid; p < M; p += BNT)
    part += 0.5f * logf(fmaxf(sS[roff(p) + p], EPSF));
#pragma unroll
  for (int off = 32; off > 0; off >>= 1) part += __shfl_down(part, off);
  if (lane == 0) red[wid] = part;
  __syncthreads();
  if (tid == 0) {
    float s = 0.0f;
#pragma unroll
    for (int w8 = 0; w8 < 8; ++w8) s += red[w8];
    ws[PART_OFF + J * 16 + d] = s;
  }

  // LB (bf16) write: row p, cols k: [L[p][0..M-1], A0[p], A1[p], 0 pad]
  unsigned* LBg = (unsigned*)ws + LBOFF + d * (MP * KW);
  constexpr int NWORDS = MP * KW;
  for (int idx = tid; idx < NWORDS; idx += BNT) {
    const int p = idx / KW;
    const int k0 = (idx - p * KW) * 2;
    unsigned short h[2];
#pragma unroll
    for (int e = 0; e < 2; ++e) {
      const int k = k0 + e;
      float v = 0.0f;
      if (p < M) {
        if (k < M) {
          if (k <= p) {
            const float dq = fmaxf(sS[roff(k) + k], EPSF);
            v = (k == p) ? sqrtf(dq) : sS[roff(p) + k] * rsqrtf(dq);
          }
        } else if (k == M)     v = sAmu[p * 2 + 0];
        else if (k == M + 1)   v = sAmu[p * 2 + 1];
      }
      h[e] = f2bf(v);
    }
    LBg[idx] = (unsigned)h[0] | ((unsigned)h[1] << 16);
  }
}

__global__ __launch_bounds__(BNT) void build_kernel(const float* __restrict__ ts,
                                                    const float* __restrict__ log_tau,
                                                    float* __restrict__ ws)
{
  __shared__ float sS[13120];   // aligned packed lower triangle (mp=160)
  __shared__ __attribute__((aligned(16))) unsigned short sUc[160 * 32]; // [hi|lo] u rows
  __shared__ __attribute__((aligned(16))) unsigned short sWc[160 * 32]; // [hi|lo] -w rows
  __shared__ float stj[152];
  __shared__ float sAmu[304];
  __shared__ float sKp[304];
  __shared__ float red[8];

  const int j = blockIdx.x >> 4;
  const int d = blockIdx.x & 15;
  if (j == 0)      build_impl<0>(d, ts, log_tau, ws, sS, sUc, sWc, stj, sAmu, sKp, red);
  else if (j == 1) build_impl<1>(d, ts, log_tau, ws, sS, sUc, sWc, stj, sAmu, sKp, red);
  else             build_impl<2>(d, ts, log_tau, ws, sS, sUc, sWc, stj, sAmu, sKp, red);
}

// ---------------------------------------------------------------------------
// Kernel B (MFMA), 64-row blocks (R5 math, R10 nt-hints): out[b,p] =
// sum_k Z'[b,k] * LB[p,k]. z is read-once and out is write-once across the
// whole pipeline -> non-temporal loads/stores keep the ~80MB stream from
// evicting the multiply-reused LB panels out of L2 (LB re-read by 32
// row-group blocks per (j,d)).
// ---------------------------------------------------------------------------
template <int M, int MP, int KS, int KT, int TOFF, int OOFF, int LBOFF>
__device__ __forceinline__ void apply_impl(const float* __restrict__ z,
                                           const unsigned* __restrict__ wsu,
                                           float* __restrict__ out,
                                           char* smem, int blk)
{
  constexpr int PT = MP / 16;           // p-tiles
  constexpr int CK = KS / 8;            // 8-col chunks per Z row
  const int d   = blk & 15;
  const int bs0 = (blk >> 4) * 64;      // 64-row group (blk>>4 in 0..31)
  const int tid = threadIdx.x;
  const int lane = tid & 63;
  const int wv   = tid >> 6;            // 4 waves, each owns a p-tile range

  unsigned short* Zs = (unsigned short*)smem;   // 64 x KS bf16

  // stage Z' tile (bf16): row r, cols k -> z[row][TOFF+k] | zf | zl | 0
  for (int idx = tid; idx < 64 * CK; idx += 256) {
    const int r = idx / CK;             // constexpr CK -> magic mul
    const int k0 = (idx - r * CK) * 8;
    const float* zr = z + (size_t)((bs0 + r) * 16 + d) * 302;
    us8_t v;
    if (k0 + 8 <= M) {
#pragma unroll
      for (int t = 0; t < 4; ++t) {
        const f32x2 f = __builtin_nontemporal_load(
            (const f32x2*)(zr + TOFF + k0 + 2 * t));   // 8B-aligned (all even)
        v[2 * t]     = f2bf(f[0]);
        v[2 * t + 1] = f2bf(f[1]);
      }
    } else {
#pragma unroll
      for (int e = 0; e < 8; ++e) {
        const int k = k0 + e;
        float f;
        if (k < M)           f = zr[TOFF + k];
        else if (k == M)     f = zr[0];
        else if (k == M + 1) f = zr[1];
        else                 f = 0.0f;
        v[e] = f2bf(f);
      }
    }
    *(us8_t*)&Zs[r * KS + k0] = v;
  }

  // zf / zl pass-through columns (exact fp32), 64 rows x 2
  if (tid < 128) {
    const int r = tid >> 1;
    const int which = tid & 1;
    const float* zr = z + (size_t)((bs0 + r) * 16 + d) * 302;
    __builtin_nontemporal_store(zr[which],
        &out[(size_t)((bs0 + r) * 16 + d) * 306 + OOFF + (which ? (M + 1) : 0)]);
  }
  __syncthreads();

  // A fragments for all 4 row-tiles: rt*16 + (lane&15), koff = (lane>>4)*8
  bf8_t afr[4][KT];
  {
    const int arow = lane & 15;
    const int koff = (lane >> 4) * 8;
#pragma unroll
    for (int rt = 0; rt < 4; ++rt)
#pragma unroll
      for (int kt = 0; kt < KT; ++kt)
        afr[rt][kt] = *(const bf8_t*)&Zs[(rt * 16 + arow) * KS + kt * 32 + koff];
  }

  const unsigned short* LBd = (const unsigned short*)(wsu + LBOFF + d * (MP * (KS / 2)));
  const int pt0 = (PT * wv) >> 2;       // disjoint p-tile range per wave
  const int pt1 = (PT * (wv + 1)) >> 2;
  for (int pt = pt0; pt < pt1; ++pt) {
    const int p = pt * 16 + (lane & 15);
    const unsigned short* bb = &LBd[p * KS + (lane >> 4) * 8];
    // hoist all KT B-fragments for this p-tile (each feeds 4 MFMAs).
    // LB loads stay CACHED (the reused operand we're protecting in L2).
    bf8_t bfr[KT];
#pragma unroll
    for (int kt = 0; kt < KT; ++kt)
      bfr[kt] = *(const bf8_t*)&bb[kt * 32];
#pragma unroll
    for (int rt = 0; rt < 4; ++rt) {
      f32x4 acc = {0.0f, 0.0f, 0.0f, 0.0f};
#pragma unroll
      for (int kt = 0; kt < KT; ++kt)
        acc = __builtin_amdgcn_mfma_f32_16x16x32_bf16(afr[rt][kt], bfr[kt], acc, 0, 0, 0);
      if (p < M) {
        const int rbase = bs0 + rt * 16 + (lane >> 4) * 4;
#pragma unroll
        for (int e = 0; e < 4; ++e)
          __builtin_nontemporal_store(acc[e],
              &out[(size_t)((rbase + e) * 16 + d) * 306 + OOFF + 1 + p]);
      }
    }
  }
}

__global__ __launch_bounds__(256) void apply_kernel(const float* __restrict__ z,
                                                    const unsigned* __restrict__ wsu,
                                                    float* __restrict__ out,
                                                    const float* __restrict__ part,
                                                    const float* __restrict__ sldj,
                                                    int last)
{
  __shared__ __attribute__((aligned(16))) char smem[21504]; // 64*168*2
  const int bid = blockIdx.x;
  if (bid == 1535 && threadIdx.x == 0) {
    // fused finalize: ldj = sldj_in + sum of 48 build partials
    float s = sldj[0];
#pragma unroll
    for (int i = 0; i < 48; ++i) s += part[i];
    out[last] = s;
  }
  if (bid < 512)       apply_impl<150, 160, 168, 5, 152, 154, LB2_OFF>(z, wsu, out, smem, bid);
  else if (bid < 1024) apply_impl<100, 112, 136, 4,  52,  52, LB1_OFF>(z, wsu, out, smem, bid - 512);
  else                 apply_impl< 50,  64,  72, 2,   2,   0, LB0_OFF>(z, wsu, out, smem, bid - 1024);
}

extern "C" void kernel_launch(void* const* d_in, const int* in_sizes, int n_in,
                              void* d_out, int out_size, void* d_ws, size_t ws_size,
                              hipStream_t stream)
{
  const float* z       = (const float*)d_in[0];  // (16,128,16,302)
  const float* ts      = (const float*)d_in[1];  // (3,50) flat
  const float* log_tau = (const float*)d_in[2];  // (16,)
  const float* sldj    = (const float*)d_in[3];  // scalar
  float* out = (float*)d_out;                    // 16*128*16*306 + 1
  float* ws  = (float*)d_ws;

  hipLaunchKernelGGL(build_kernel, dim3(48), dim3(BNT), 0, stream, ts, log_tau, ws);
  hipLaunchKernelGGL(apply_kernel, dim3(1536), dim3(256), 0, stream,
                     z, (const unsigned*)ws, out,
                     ws + PART_OFF, sldj, out_size - 1);
}

// Round 11
// 164.113 us; speedup vs baseline: 1.4441x; 1.2059x over previous
//
#include <hip/hip_runtime.h>

// ws layout (32-bit word offsets). LB arrays are bf16-packed (2 per word):
// LB[j][d] has MP rows, KS bf16 columns (row stride KS), row p holds
// [ L[p][0..M-1], A_mu[p][0], A_mu[p][1], zeros... ]
#define LB0_OFF 0         // 16 * (64*72/2)   = 16*2304  = 36864
#define LB1_OFF 36864     // 16 * (112*136/2) = 16*7616  = 121856
#define LB2_OFF 158720    // 16 * (160*168/2) = 16*13440 = 215040
#define PART_OFF 373760   // 48 partial ldj sums (float)

typedef __attribute__((ext_vector_type(8))) short bf8_t;    // 8 bf16 (4 VGPR)
typedef __attribute__((ext_vector_type(8))) unsigned short us8_t;
typedef __attribute__((ext_vector_type(4))) float f32x4;

__device__ __forceinline__ int tri_i(int p) { return (p * (p + 1)) >> 1; }

// Collision-free 16B-aligned packed-triangle layout: row p is padded to
// 4*ceil((p+1)/4) floats. Cumulative start (closed form, verified):
//   roff(p) = 4*(T+1)*(2T+r),  T = p>>2, r = p&3
// roff(159)+159 = 13119 -> sS size 13120 exactly covers all rows.
__device__ __forceinline__ int roff(int p) {
  const int T = p >> 2, r = p & 3;
  return ((T + 1) * (2 * T + r)) << 2;
}

__device__ __forceinline__ void tri_decode(int e, int& r, int& c) {
  r = (int)((sqrtf(8.0f * (float)e + 1.0f) - 1.0f) * 0.5f);
  if (tri_i(r + 1) <= e) ++r;
  if (tri_i(r) > e) --r;
  c = e - tri_i(r);
}

// fp32 -> bf16, round-nearest-even
__device__ __forceinline__ unsigned short f2bf(float f) {
  unsigned u = __builtin_bit_cast(unsigned, f);
  u = (u + 0x7FFFu + ((u >> 16) & 1u)) >> 16;
  return (unsigned short)u;
}
__device__ __forceinline__ float bf2f(unsigned short h) {
  return __builtin_bit_cast(float, ((unsigned)h) << 16);
}

// uniform-lane broadcast via v_readlane (no DS pipe, low latency)
__device__ __forceinline__ float blane(float v, int l) {
  return __builtin_bit_cast(float, __builtin_amdgcn_readlane(__builtin_bit_cast(int, v), l));
}
__device__ __forceinline__ float fastrcp(float x) { return __builtin_amdgcn_rcpf(x); }

#define BNT 512   // build_kernel threads (8 waves)
#define EPSF 1e-4f

// ---------------------------------------------------------------------------
// Kernel A (champion, R7): per (j,d) Sigma (padded to MP, identity tail),
// blocked raw-Schur Cholesky (bw=16) with MFMA phase C.
//  - phase A: 16x16 diag factor in registers (waves 0-2), readlane broadcasts
//  - phase B: row-solve 1 thread/row, b128 rows; emits split-bf16 U/W rows
//  - phase C: trailing Schur update via mfma_f32_16x16x32_bf16 (hi/lo split,
//    ~2^-17 rel err; pivot clamp max(d,EPS) guards sqrt/log/rcp)
//  - 2 barriers/panel; ldj via wave shfl reduce; j-templated (magic-mul divs)
// ---------------------------------------------------------------------------
template <int J>
__device__ __forceinline__ void build_impl(int d,
                                           const float* __restrict__ ts,
                                           const float* __restrict__ log_tau,
                                           float* __restrict__ ws,
                                           float* sS,
                                           unsigned short* sUc, unsigned short* sWc,
                                           float* stj, float* sAmu, float* sKp,
                                           float* red)
{
  constexpr int M  = (J + 1) * 50;
  constexpr int MP = (J == 0) ? 64 : ((J == 1) ? 112 : 160);
  constexpr int KS = (J == 0) ? 72 : ((J == 1) ? 136 : 168);
  constexpr int LBOFF = (J == 0) ? LB0_OFF : ((J == 1) ? LB1_OFF : LB2_OFF);
  constexpr float TPSJ = (J == 0) ? 10.0f : ((J == 1) ? 20.0f : 30.0f);
  constexpr int KW = KS / 2;
  constexpr int TOT = (MP * (MP + 1)) / 2;
  constexpr int NPAN = MP / 16;

  const int tid  = threadIdx.x;
  const int lane = tid & 63;
  const int wid  = tid >> 6;        // 8 waves

  const float tau = expf(log_tau[d]);
  const float cc = 1.0f / (2.0f * tau * tau);

  for (int i = tid; i < M; i += BNT) stj[i] = ts[i];
  __syncthreads();

  const float k01 = expf(-TPSJ * TPSJ * cc);
  const float det = 1.0f - k01 * k01;
  const float i00 = 1.0f / det;
  const float i01 = -k01 / det;

  for (int p = tid; p < M; p += BNT) {
    float tp = stj[p];
    float kp0 = expf(-tp * tp * cc);
    float dt = tp - TPSJ;
    float kp1 = expf(-dt * dt * cc);
    sKp[p * 2 + 0] = kp0; sKp[p * 2 + 1] = kp1;
    sAmu[p * 2 + 0] = fmaf(kp0, i00, kp1 * i01);
    sAmu[p * 2 + 1] = fmaf(kp0, i01, kp1 * i00);
  }
  __syncthreads();

  // Sigma, padded: rows >= M are identity -> log contrib 0, L tail ignored.
  for (int e = tid; e < TOT; e += BNT) {
    int r, q;
    tri_decode(e, r, q);
    float v;
    if (r < M) {
      float dq = stj[r] - stj[q];
      v = expf(-dq * dq * cc)
        - fmaf(sAmu[r * 2], sKp[q * 2], sAmu[r * 2 + 1] * sKp[q * 2 + 1]);
      if (r == q) v += EPSF;
    } else {
      v = (r == q) ? 1.0f : 0.0f;
    }
    sS[roff(r) + q] = v;
  }
  __syncthreads();

  // ---- Blocked raw-Schur Cholesky, bw == 16 always ----
  const int tr = lane & 15;
#pragma unroll 1
  for (int pb = 0; pb < NPAN; ++pb) {
    const int kb = pb << 4;
    const int be = kb + 16;
    const int rbase = roff(kb + tr) + kb;   // 16B-aligned

    // phase A: diag block factor in registers, replicated in waves 0..2.
    float rd[16];
    float invd[16];
    if (wid < 3) {
      const float4* rp = (const float4*)&sS[rbase];
#pragma unroll
      for (int c4 = 0; c4 < 4; ++c4) *(float4*)&rd[c4 * 4] = rp[c4];
#pragma unroll
      for (int kk = 0; kk < 15; ++kk) {
        const float dkk = fmaxf(blane(rd[kk], kk), EPSF);   // clamp (no-op in exact math)
        const float ri = fastrcp(dkk);
        invd[kk] = ri;
        const float c = -rd[kk] * ri;
#pragma unroll
        for (int q2 = kk + 1; q2 < 16; ++q2) {
          const float cq2 = blane(rd[kk], q2);
          if (tr > kk && q2 <= tr) rd[q2] = fmaf(c, cq2, rd[q2]);
        }
      }
      invd[15] = fastrcp(fmaxf(blane(rd[15], 15), EPSF));
    }

    // phase B (no barrier after A: same waves): row-solve, 1 thread per row.
    // Emits split-bf16 rows for the MFMA trailing update.
    if (be < MP) {
      const int i = be + tid;
      if (i < MP) {
        const int base = roff(i) + kb;      // 16B-aligned
        float r[16];
        const float4* rp = (const float4*)&sS[base];
#pragma unroll
        for (int c4 = 0; c4 < 4; ++c4) *(float4*)&r[c4 * 4] = rp[c4];
#pragma unroll
        for (int kk = 0; kk < 15; ++kk) {
          const float c = r[kk] * invd[kk];
#pragma unroll
          for (int q = kk + 1; q < 16; ++q)
            r[q] = fmaf(-c, blane(rd[kk], q), r[q]);
        }
        float4* sp = (float4*)&sS[base];
#pragma unroll
        for (int c4 = 0; c4 < 4; ++c4) sp[c4] = *(float4*)&r[c4 * 4];
        // split-bf16: Uc = [hi(u) | lo(u)], Wc = [hi(-w) | lo(-w)], K=32
        unsigned short uc[32], wc[32];
#pragma unroll
        for (int t = 0; t < 16; ++t) {
          const float uv = r[t];
          const unsigned short uhh = f2bf(uv);
          uc[t] = uhh; uc[16 + t] = f2bf(uv - bf2f(uhh));
          const float wv = -(r[t] * invd[t]);
          const unsigned short whh = f2bf(wv);
          wc[t] = whh; wc[16 + t] = f2bf(wv - bf2f(whh));
        }
        unsigned short* ucp = &sUc[i * 32];
        unsigned short* wcp = &sWc[i * 32];
#pragma unroll
        for (int c8 = 0; c8 < 4; ++c8) {
          *(us8_t*)&ucp[c8 * 8] = *(us8_t*)&uc[c8 * 8];
          *(us8_t*)&wcp[c8 * 8] = *(us8_t*)&wc[c8 * 8];
        }
      }
    }
    __syncthreads();

    // factored diag -> sS (predicated: q > tr is beyond row's valid cols)
    if (wid == 0 && lane < 16) {
#pragma unroll
      for (int q = 0; q < 16; ++q) if (q <= tr) sS[rbase + q] = rd[q];
    }

    // phase C (MFMA): trailing Schur update, one 16x16 tile per iteration.
    // D = S_tile + [Wh|Wl].[Uh|Ul]^T + [Wl|Wh].[Uh|Ul]^T  (W pre-negated).
    if (be < MP) {
      const int ntr = (MP - be) >> 4;
      const int ntiles = (ntr * (ntr + 1)) >> 1;
      const int rloc = lane & 15;
      const int koff = (lane >> 4) * 8;
      for (int t = wid; t < ntiles; t += 8) {
        int ta, tb;
        tri_decode(t, ta, tb);              // tb <= ta
        const int R0 = be + (ta << 4);
        const int Q0 = be + (tb << 4);
        const bf8_t af  = *(const bf8_t*)&sWc[(R0 + rloc) * 32 + koff];
        const bf8_t af2 = *(const bf8_t*)&sWc[(R0 + rloc) * 32 + (koff ^ 16)];
        const bf8_t bfv = *(const bf8_t*)&sUc[(Q0 + rloc) * 32 + koff];
        const int drow = R0 + (lane >> 4) * 4;
        const int qq = Q0 + rloc;
        int ra[4];
        f32x4 acc;
#pragma unroll
        for (int e = 0; e < 4; ++e) {
          ra[e] = roff(drow + e) + qq;      // qq>row reads in-bounds junk,
          acc[e] = sS[ra[e]];               // write-predicated below
        }
        acc = __builtin_amdgcn_mfma_f32_16x16x32_bf16(af,  bfv, acc, 0, 0, 0);
        acc = __builtin_amdgcn_mfma_f32_16x16x32_bf16(af2, bfv, acc, 0, 0, 0);
#pragma unroll
        for (int e = 0; e < 4; ++e)
          if (qq <= drow + e) sS[ra[e]] = acc[e];
      }
    }
    __syncthreads();
  }

  // ldj partial: sum 0.5*log(d_p) over real rows; wave reduce
  float part = 0.0f;
  for (int p = tid; p < M; p += BNT)
    part += 0.5f * logf(fmaxf(sS[roff(p) + p], EPSF));
#pragma unroll
  for (int off = 32; off > 0; off >>= 1) part += __shfl_down(part, off);
  if (lane == 0) red[wid] = part;
  __syncthreads();
  if (tid == 0) {
    float s = 0.0f;
#pragma unroll
    for (int w8 = 0; w8 < 8; ++w8) s += red[w8];
    ws[PART_OFF + J * 16 + d] = s;
  }

  // LB (bf16) write: row p, cols k: [L[p][0..M-1], A0[p], A1[p], 0 pad]
  unsigned* LBg = (unsigned*)ws + LBOFF + d * (MP * KW);
  constexpr int NWORDS = MP * KW;
  for (int idx = tid; idx < NWORDS; idx += BNT) {
    const int p = idx / KW;
    const int k0 = (idx - p * KW) * 2;
    unsigned short h[2];
#pragma unroll
    for (int e = 0; e < 2; ++e) {
      const int k = k0 + e;
      float v = 0.0f;
      if (p < M) {
        if (k < M) {
          if (k <= p) {
            const float dq = fmaxf(sS[roff(k) + k], EPSF);
            v = (k == p) ? sqrtf(dq) : sS[roff(p) + k] * rsqrtf(dq);
          }
        } else if (k == M)     v = sAmu[p * 2 + 0];
        else if (k == M + 1)   v = sAmu[p * 2 + 1];
      }
      h[e] = f2bf(v);
    }
    LBg[idx] = (unsigned)h[0] | ((unsigned)h[1] << 16);
  }
}

__global__ __launch_bounds__(BNT) void build_kernel(const float* __restrict__ ts,
                                                    const float* __restrict__ log_tau,
                                                    float* __restrict__ ws)
{
  __shared__ float sS[13120];   // aligned packed lower triangle (mp=160)
  __shared__ __attribute__((aligned(16))) unsigned short sUc[160 * 32]; // [hi|lo] u rows
  __shared__ __attribute__((aligned(16))) unsigned short sWc[160 * 32]; // [hi|lo] -w rows
  __shared__ float stj[152];
  __shared__ float sAmu[304];
  __shared__ float sKp[304];
  __shared__ float red[8];

  const int j = blockIdx.x >> 4;
  const int d = blockIdx.x & 15;
  if (j == 0)      build_impl<0>(d, ts, log_tau, ws, sS, sUc, sWc, stj, sAmu, sKp, red);
  else if (j == 1) build_impl<1>(d, ts, log_tau, ws, sS, sUc, sWc, stj, sAmu, sKp, red);
  else             build_impl<2>(d, ts, log_tau, ws, sS, sUc, sWc, stj, sAmu, sKp, red);
}

// ---------------------------------------------------------------------------
// Kernel B (MFMA), 64-row blocks (champion, R5 math): out[b,p] =
// sum_k Z'[b,k] * LB[p,k], bf16 16x16x32. Each wave holds A-fragments for
// all 64 rows and owns a disjoint p-tile range -> each LB fragment load
// feeds 4 MFMAs; LB read 1x per block from L2.
// ---------------------------------------------------------------------------
template <int M, int MP, int KS, int KT, int TOFF, int OOFF, int LBOFF>
__device__ __forceinline__ void apply_impl(const float* __restrict__ z,
                                           const unsigned* __restrict__ wsu,
                                           float* __restrict__ out,
                                           char* smem, int blk)
{
  constexpr int PT = MP / 16;           // p-tiles
  constexpr int CK = KS / 8;            // 8-col chunks per Z row
  const int d   = blk & 15;
  const int bs0 = (blk >> 4) * 64;      // 64-row group (blk>>4 in 0..31)
  const int tid = threadIdx.x;
  const int lane = tid & 63;
  const int wv   = tid >> 6;            // 4 waves, each owns a p-tile range

  unsigned short* Zs = (unsigned short*)smem;   // 64 x KS bf16

  // stage Z' tile (bf16): row r, cols k -> z[row][TOFF+k] | zf | zl | 0
  for (int idx = tid; idx < 64 * CK; idx += 256) {
    const int r = idx / CK;             // constexpr CK -> magic mul
    const int k0 = (idx - r * CK) * 8;
    const float* zr = z + (size_t)((bs0 + r) * 16 + d) * 302;
    us8_t v;
    if (k0 + 8 <= M) {
#pragma unroll
      for (int t = 0; t < 4; ++t) {
        const float2 f = *(const float2*)(zr + TOFF + k0 + 2 * t);
        v[2 * t]     = f2bf(f.x);
        v[2 * t + 1] = f2bf(f.y);
      }
    } else {
#pragma unroll
      for (int e = 0; e < 8; ++e) {
        const int k = k0 + e;
        float f;
        if (k < M)           f = zr[TOFF + k];
        else if (k == M)     f = zr[0];
        else if (k == M + 1) f = zr[1];
        else                 f = 0.0f;
        v[e] = f2bf(f);
      }
    }
    *(us8_t*)&Zs[r * KS + k0] = v;
  }

  // zf / zl pass-through columns (exact fp32), 64 rows x 2
  if (tid < 128) {
    const int r = tid >> 1;
    const int which = tid & 1;
    const float* zr = z + (size_t)((bs0 + r) * 16 + d) * 302;
    out[(size_t)((bs0 + r) * 16 + d) * 306 + OOFF + (which ? (M + 1) : 0)] = zr[which];
  }
  __syncthreads();

  // A fragments for all 4 row-tiles: rt*16 + (lane&15), koff = (lane>>4)*8
  bf8_t afr[4][KT];
  {
    const int arow = lane & 15;
    const int koff = (lane >> 4) * 8;
#pragma unroll
    for (int rt = 0; rt < 4; ++rt)
#pragma unroll
      for (int kt = 0; kt < KT; ++kt)
        afr[rt][kt] = *(const bf8_t*)&Zs[(rt * 16 + arow) * KS + kt * 32 + koff];
  }

  const unsigned short* LBd = (const unsigned short*)(wsu + LBOFF + d * (MP * (KS / 2)));
  const int pt0 = (PT * wv) >> 2;       // disjoint p-tile range per wave
  const int pt1 = (PT * (wv + 1)) >> 2;
  for (int pt = pt0; pt < pt1; ++pt) {
    const int p = pt * 16 + (lane & 15);
    const unsigned short* bb = &LBd[p * KS + (lane >> 4) * 8];
    // hoist all KT B-fragments for this p-tile (each feeds 4 MFMAs)
    bf8_t bfr[KT];
#pragma unroll
    for (int kt = 0; kt < KT; ++kt)
      bfr[kt] = *(const bf8_t*)&bb[kt * 32];   // 16B global load (L2)
#pragma unroll
    for (int rt = 0; rt < 4; ++rt) {
      f32x4 acc = {0.0f, 0.0f, 0.0f, 0.0f};
#pragma unroll
      for (int kt = 0; kt < KT; ++kt)
        acc = __builtin_amdgcn_mfma_f32_16x16x32_bf16(afr[rt][kt], bfr[kt], acc, 0, 0, 0);
      if (p < M) {
        const int rbase = bs0 + rt * 16 + (lane >> 4) * 4;
#pragma unroll
        for (int e = 0; e < 4; ++e)
          out[(size_t)((rbase + e) * 16 + d) * 306 + OOFF + 1 + p] = acc[e];
      }
    }
  }
}

__global__ __launch_bounds__(256) void apply_kernel(const float* __restrict__ z,
                                                    const unsigned* __restrict__ wsu,
                                                    float* __restrict__ out,
                                                    const float* __restrict__ part,
                                                    const float* __restrict__ sldj,
                                                    int last)
{
  __shared__ __attribute__((aligned(16))) char smem[21504]; // 64*168*2
  const int bid = blockIdx.x;
  if (bid == 1535 && threadIdx.x == 0) {
    // fused finalize: ldj = sldj_in + sum of 48 build partials
    float s = sldj[0];
#pragma unroll
    for (int i = 0; i < 48; ++i) s += part[i];
    out[last] = s;
  }
  if (bid < 512)       apply_impl<150, 160, 168, 5, 152, 154, LB2_OFF>(z, wsu, out, smem, bid);
  else if (bid < 1024) apply_impl<100, 112, 136, 4,  52,  52, LB1_OFF>(z, wsu, out, smem, bid - 512);
  else                 apply_impl< 50,  64,  72, 2,   2,   0, LB0_OFF>(z, wsu, out, smem, bid - 1024);
}

extern "C" void kernel_launch(void* const* d_in, const int* in_sizes, int n_in,
                              void* d_out, int out_size, void* d_ws, size_t ws_size,
                              hipStream_t stream)
{
  const float* z       = (const float*)d_in[0];  // (16,128,16,302)
  const float* ts      = (const float*)d_in[1];  // (3,50) flat
  const float* log_tau = (const float*)d_in[2];  // (16,)
  const float* sldj    = (const float*)d_in[3];  // scalar
  float* out = (float*)d_out;                    // 16*128*16*306 + 1
  float* ws  = (float*)d_ws;

  hipLaunchKernelGGL(build_kernel, dim3(48), dim3(BNT), 0, stream, ts, log_tau, ws);
  hipLaunchKernelGGL(apply_kernel, dim3(1536), dim3(256), 0, stream,
                     z, (const unsigned*)ws, out,
                     ws + PART_OFF, sldj, out_size - 1);
}